// Round 3
// baseline (544.360 us; speedup 1.0000x reference)
//
#include <hip/hip_runtime.h>
#include <math.h>

#define B 32
#define C 1536
#define D2 3072
#define L 1024
#define KC 64      // k-chunk per staging pass (16 float4 quads)
#define KQ 16      // quads per row per chunk
#define CH 16      // flash L-chunks -> grid 16x32, 64 wave-partials per b
#define LPW 16     // l's per wave = L/(CH*4)

__device__ inline float dot4(float4 a, float4 b) {
    return a.x * b.x + a.y * b.y + a.z * b.z + a.w * b.w;
}
__device__ inline float4 ld4(const float* p) { return *(const float4*)p; }
__device__ inline void   st4(float* p, float4 v) { *(float4*)p = v; }
__device__ inline float4 add4(float4 a, float4 b) {
    return make_float4(a.x + b.x, a.y + b.y, a.z + b.z, a.w + b.w);
}

// swizzled LDS quad address (float index): row*KC + (q ^ ((row>>2)&7))*4
__device__ inline int sw(int row, int q) {
    return row * KC + ((q ^ ((row >> 2) & 7)) << 2);
}
// scalar element (row, k) inside the same layout
__device__ inline int swe(int row, int k) {
    return row * KC + (((k >> 2) ^ ((row >> 2) & 7)) << 2) + (k & 3);
}

// ---------------- split-K GEMM, 32b x 128j tile, 4x4/thread ----------------
// AM: 0 = A plain 32xK row-major
//     1 = A = sum of nsl partial slices (32xK each) + abias   (theta for u-GEMM)
//     2 = A = feats construct: k<C -> xres ; k>=C -> sum partials + abias + xres
// BM: 0 = W is NxK row-major (w.T GEMM)
//     1 = W is KxN row-major (phi_w): stage with in-LDS transpose
template <int AM, int BM>
__global__ __launch_bounds__(256) void gemm_k(const float* __restrict__ Asrc,
                                              const float* __restrict__ abias,
                                              const float* __restrict__ xres,
                                              const float* __restrict__ W,
                                              float* __restrict__ part,
                                              int N, int K, int kchunks, int nsl) {
    __shared__ float xs[32 * KC];    // 8 KB
    __shared__ float wsm[128 * KC];  // 32 KB
    int tid = threadIdx.x;
    int j0 = blockIdx.x * 128;
    int kb = blockIdx.y;
    int tb = tid & 7;        // 8 b-groups of 4
    int tj = tid >> 3;       // 32 j-groups of 4

    float4 acc[4];
    #pragma unroll
    for (int r = 0; r < 4; ++r) acc[r] = make_float4(0.f, 0.f, 0.f, 0.f);

    for (int c = 0; c < kchunks; ++c) {
        int k0 = (kb * kchunks + c) * KC;
        __syncthreads();
        // ---- stage A ----
        #pragma unroll
        for (int p = 0; p < 2; ++p) {
            int f = tid + 256 * p;
            int row = f >> 4, q = f & 15;
            int k = k0 + 4 * q;
            float4 v;
            if (AM == 0) {
                v = ld4(Asrc + (size_t)row * K + k);
            } else if (AM == 1) {
                v = ld4(abias + k);
                #pragma unroll
                for (int s = 0; s < 12; ++s)
                    v = add4(v, ld4(Asrc + ((size_t)s * 32 + row) * K + k));
            } else {
                if (k0 < C) {
                    v = ld4(xres + (size_t)row * C + k);
                } else {
                    int jj = k - C;
                    v = add4(ld4(abias + jj), ld4(xres + (size_t)row * C + jj));
                    #pragma unroll
                    for (int s = 0; s < 12; ++s)
                        v = add4(v, ld4(Asrc + ((size_t)s * 32 + row) * C + jj));
                }
            }
            st4(xs + sw(row, q), v);
        }
        // ---- stage B ----
        if (BM == 0) {
            #pragma unroll
            for (int p = 0; p < 8; ++p) {
                int f = tid + 256 * p;
                int row = f >> 4, q = f & 15;
                float4 v = ld4(W + (size_t)(j0 + row) * K + k0 + 4 * q);
                st4(wsm + sw(row, q), v);
            }
        } else {
            // W is KxN: read rows of W (contiguous in j), transpose into LDS
            #pragma unroll
            for (int p = 0; p < 8; ++p) {
                int f = tid + 256 * p;
                int kk = f >> 5, jq = f & 31;  // kk: 0..63, jq: 0..31 (j-quad)
                float4 v = ld4(W + (size_t)(k0 + kk) * N + j0 + 4 * jq);
                wsm[swe(4 * jq + 0, kk)] = v.x;
                wsm[swe(4 * jq + 1, kk)] = v.y;
                wsm[swe(4 * jq + 2, kk)] = v.z;
                wsm[swe(4 * jq + 3, kk)] = v.w;
            }
        }
        __syncthreads();
        // ---- compute ----
        #pragma unroll
        for (int kq = 0; kq < KQ; ++kq) {
            float4 xq[4], wq[4];
            #pragma unroll
            for (int r = 0; r < 4; ++r) {
                xq[r] = ld4(xs + sw(4 * tb + r, kq));
                wq[r] = ld4(wsm + sw(4 * tj + r, kq));
            }
            #pragma unroll
            for (int r = 0; r < 4; ++r) {
                acc[r].x += dot4(xq[r], wq[0]);
                acc[r].y += dot4(xq[r], wq[1]);
                acc[r].z += dot4(xq[r], wq[2]);
                acc[r].w += dot4(xq[r], wq[3]);
            }
        }
    }
    #pragma unroll
    for (int r = 0; r < 4; ++r)
        st4(part + ((size_t)kb * 32 + 4 * tb + r) * N + j0 + 4 * tj, acc[r]);
}

// ---------------- split-K reduce + bias + layernorm + relu (32 rows) ----------------
__global__ __launch_bounds__(256) void reduce_ln_relu(const float* __restrict__ part,
                                                      const float* __restrict__ bias,
                                                      const float* __restrict__ g,
                                                      const float* __restrict__ bt,
                                                      float* __restrict__ out,
                                                      int ksplit) {
    int b = blockIdx.x, tid = threadIdx.x;
    __shared__ float r1[4], r2[4];
    float lv[6];
    float s1 = 0.f, s2 = 0.f;
    #pragma unroll
    for (int t = 0; t < 6; ++t) {
        int c = tid + 256 * t;
        float acc = 0.f;
        for (int kk = 0; kk < ksplit; ++kk) acc += part[((size_t)kk * 32 + b) * C + c];
        acc += bias[c];
        lv[t] = acc; s1 += acc; s2 += acc * acc;
    }
    #pragma unroll
    for (int off = 32; off > 0; off >>= 1) {
        s1 += __shfl_xor(s1, off, 64);
        s2 += __shfl_xor(s2, off, 64);
    }
    int wave = tid >> 6, lane = tid & 63;
    if (lane == 0) { r1[wave] = s1; r2[wave] = s2; }
    __syncthreads();
    s1 = r1[0] + r1[1] + r1[2] + r1[3];
    s2 = r2[0] + r2[1] + r2[2] + r2[3];
    float mu = s1 / (float)C;
    float var = s2 / (float)C - mu * mu;
    float rstd = 1.0f / sqrtf(var + 1e-5f);
    #pragma unroll
    for (int t = 0; t < 6; ++t) {
        int c = tid + 256 * t;
        float y = (lv[t] - mu) * rstd * g[c] + bt[c];
        out[(size_t)b * C + c] = fmaxf(y, 0.f);
    }
}

// ---------------- flash: u-partial reduce + scores + online softmax + weighted accum ----
__global__ __launch_bounds__(256) void flash_k(const float* __restrict__ partU, // 12 x 32 x C
                                               const float* __restrict__ lfb,   // 32 x L x C
                                               float* __restrict__ pm,
                                               float* __restrict__ ps,
                                               float* __restrict__ pv) {
    int chunk = blockIdx.x;          // 0..CH-1
    int b = blockIdx.y;              // 0..31
    int wave = threadIdx.x >> 6;     // 0..3
    int lane = threadIdx.x & 63;
    int tid = threadIdx.x;
    int widx = chunk * 4 + wave;     // 0..63

    const float scale = 39.19183588453085f;  // sqrt(1536)

    // reduce u = sum of 12 partial slices, once per block, into LDS
    __shared__ float uld[C];
    for (int c0 = tid; c0 < C; c0 += 256) {
        float s = 0.f;
        #pragma unroll
        for (int ss = 0; ss < 12; ++ss)
            s += partU[((size_t)ss * 32 + b) * C + c0];
        uld[c0] = s;
    }
    __syncthreads();

    float uu[24];
    #pragma unroll
    for (int t = 0; t < 6; ++t)
        *(float4*)(uu + 4 * t) = ld4(uld + 4 * lane + 256 * t);

    float m = -INFINITY, s = 0.f;
    float vv[24];
    #pragma unroll
    for (int t = 0; t < 24; ++t) vv[t] = 0.f;

    int l0 = chunk * (L / CH) + wave;        // stride 4 within chunk
    for (int i = 0; i < LPW; ++i) {
        int l = l0 + i * 4;
        const float* row = lfb + ((size_t)b * L + l) * C;
        float xx[24];
        #pragma unroll
        for (int t = 0; t < 6; ++t)
            *(float4*)(xx + 4 * t) = ld4(row + 4 * lane + 256 * t);
        float d = 0.f;
        #pragma unroll
        for (int t = 0; t < 24; ++t) d += xx[t] * uu[t];
        #pragma unroll
        for (int off = 32; off > 0; off >>= 1) d += __shfl_xor(d, off, 64);
        float score = d * scale;
        float mn = fmaxf(m, score);
        float alpha = __expf(m - mn);        // 0 when m == -inf
        float p = __expf(score - mn);
        s = s * alpha + p;
        #pragma unroll
        for (int t = 0; t < 24; ++t) vv[t] = vv[t] * alpha + p * xx[t];
        m = mn;
    }

    if (lane == 0) { pm[b * 64 + widx] = m; ps[b * 64 + widx] = s; }
    float* pvb = pv + ((size_t)b * 64 + widx) * C;
    #pragma unroll
    for (int t = 0; t < 6; ++t)
        st4(pvb + 4 * lane + 256 * t, *(float4*)(vv + 4 * t));
}

// ---------------- combine wave-partials -> v[b][c] ----------------
__global__ __launch_bounds__(256) void combine_k(const float* __restrict__ pm,
                                                 const float* __restrict__ ps,
                                                 const float* __restrict__ pv,
                                                 float* __restrict__ v) {
    int cc = blockIdx.x;             // 0..5
    int b = blockIdx.y;              // 0..31
    int tid = threadIdx.x;
    __shared__ float coef[64];
    if (tid < 64) {
        float mj = pm[b * 64 + tid];
        float M = mj;
        #pragma unroll
        for (int off = 32; off > 0; off >>= 1) M = fmaxf(M, __shfl_xor(M, off, 64));
        float ej = expf(mj - M);
        float S = ps[b * 64 + tid] * ej;
        #pragma unroll
        for (int off = 32; off > 0; off >>= 1) S += __shfl_xor(S, off, 64);
        coef[tid] = ej / S;
    }
    __syncthreads();
    int c = cc * 256 + tid;
    float acc = 0.f;
    #pragma unroll 8
    for (int j = 0; j < 64; ++j)
        acc += coef[j] * pv[((size_t)b * 64 + j) * C + c];
    v[(size_t)b * C + c] = acc;
}

// ---------------- final: reduce fcn partials + bias + relu + 4 head dots ----------------
__global__ __launch_bounds__(256) void final_k(const float* __restrict__ partH, // 24 x 32 x D2
                                               const float* __restrict__ fcn_b,
                                               const float* __restrict__ w1, const float* __restrict__ b1,
                                               const float* __restrict__ w2, const float* __restrict__ b2,
                                               const float* __restrict__ w3, const float* __restrict__ b3,
                                               const float* __restrict__ wt, const float* __restrict__ bt,
                                               float* __restrict__ out) {
    int b = blockIdx.x;
    int tid = threadIdx.x;
    float ph0 = 0.f, ph1 = 0.f, ph2 = 0.f, ptv = 0.f;
    #pragma unroll
    for (int t = 0; t < 12; ++t) {
        int j = tid + 256 * t;
        float s = 0.f;
        #pragma unroll 8
        for (int ss = 0; ss < 24; ++ss)
            s += partH[((size_t)ss * 32 + b) * D2 + j];
        s += fcn_b[j];
        s = fmaxf(s, 0.f);
        ptv += s * wt[j];
        int jj = tid + 256 * (t & 3);
        if (t < 4)       ph0 += s * w1[jj];
        else if (t < 8)  ph1 += s * w2[jj];
        else             ph2 += s * w3[jj];
    }
    #pragma unroll
    for (int off = 32; off > 0; off >>= 1) {
        ph0 += __shfl_xor(ph0, off, 64);
        ph1 += __shfl_xor(ph1, off, 64);
        ph2 += __shfl_xor(ph2, off, 64);
        ptv += __shfl_xor(ptv, off, 64);
    }
    __shared__ float red[4][4];
    int wave = tid >> 6, lane = tid & 63;
    if (lane == 0) {
        red[wave][0] = ph0; red[wave][1] = ph1; red[wave][2] = ph2; red[wave][3] = ptv;
    }
    __syncthreads();
    if (tid < 4) {
        float v = red[0][tid] + red[1][tid] + red[2][tid] + red[3][tid];
        float bias = (tid == 0) ? b1[0] : (tid == 1) ? b2[0] : (tid == 2) ? b3[0] : bt[0];
        out[b * 4 + tid] = v + bias;
    }
}

extern "C" void kernel_launch(void* const* d_in, const int* in_sizes, int n_in,
                              void* d_out, int out_size, void* d_ws, size_t ws_size,
                              hipStream_t stream) {
    (void)in_sizes; (void)n_in; (void)out_size; (void)ws_size;
    const float* x       = (const float*)d_in[0];
    const float* lfb     = (const float*)d_in[1];
    const float* theta_w = (const float*)d_in[2];
    const float* theta_b = (const float*)d_in[3];
    const float* phi_w   = (const float*)d_in[4];
    // d_in[5] = phi_b: additive per-row constant in softmax -> drops out
    const float* gi_w    = (const float*)d_in[6];
    const float* gi_b    = (const float*)d_in[7];
    const float* ln_g    = (const float*)d_in[8];
    const float* ln_b    = (const float*)d_in[9];
    const float* fc_w    = (const float*)d_in[10];
    const float* fc_b    = (const float*)d_in[11];
    const float* fcn_w   = (const float*)d_in[12];
    const float* fcn_b   = (const float*)d_in[13];
    const float* w1 = (const float*)d_in[14]; const float* b1 = (const float*)d_in[15];
    const float* w2 = (const float*)d_in[16]; const float* b2 = (const float*)d_in[17];
    const float* w3 = (const float*)d_in[18]; const float* b3 = (const float*)d_in[19];
    const float* wt = (const float*)d_in[20]; const float* bt = (const float*)d_in[21];
    float* out = (float*)d_out;
    float* w = (float*)d_ws;

    // workspace layout (floats), all disjoint (~30 MB)
    float* partT = w;                  // 12*32*1536 = 589824
    float* partU = w + 589824;         // 589824
    float* partG = w + 1179648;        // 589824
    float* partF = w + 1769472;        // 589824
    float* partH = w + 2359296;        // 24*32*3072 = 2359296
    float* pv    = w + 4718592;        // 32*64*1536 = 3145728
    float* pm    = w + 7864320;        // 2048
    float* ps    = w + 7866368;        // 2048
    float* vbuf  = w + 7868416;        // 49152
    float* oln   = w + 7917568;        // 49152

    // 1. partT = split-K slices of x @ theta_w.T
    gemm_k<0, 0><<<dim3(12, 12), 256, 0, stream>>>(x, nullptr, nullptr, theta_w, partT, C, C, 2, 0);
    // 2. partU = split-K slices of (reduce(partT)+theta_b) @ phi_w   (B transposed in staging)
    gemm_k<1, 1><<<dim3(12, 12), 256, 0, stream>>>(partT, theta_b, nullptr, phi_w, partU, C, C, 2, 12);
    // 3. flash over lfb (reduces partU -> u internally)
    flash_k<<<dim3(CH, B), 256, 0, stream>>>(partU, lfb, pm, ps, pv);
    // 4. combine partials -> vbuf
    combine_k<<<dim3(6, B), 256, 0, stream>>>(pm, ps, pv, vbuf);
    // 5. partG = split-K slices of vbuf @ gi_w.T
    gemm_k<0, 0><<<dim3(12, 12), 256, 0, stream>>>(vbuf, nullptr, nullptr, gi_w, partG, C, C, 2, 0);
    // 6. oln = relu(LN(reduce(partG)+gi_b))
    reduce_ln_relu<<<B, 256, 0, stream>>>(partG, gi_b, ln_g, ln_b, oln, 12);
    // 7. partF = split-K slices of oln @ fc_w.T
    gemm_k<0, 0><<<dim3(12, 12), 256, 0, stream>>>(oln, nullptr, nullptr, fc_w, partF, C, C, 2, 0);
    // 8. partH = split-K slices of feats @ fcn_w.T, feats built in staging from x/partF/fc_b
    gemm_k<2, 0><<<dim3(24, 24), 256, 0, stream>>>(partF, fc_b, x, fcn_w, partH, D2, D2, 2, 12);
    // 9. reduce + bias + relu + 4 head dots
    final_k<<<B, 256, 0, stream>>>(partH, fcn_b, w1, b1, w2, b2, w3, b3, wt, bt, out);
}

// Round 4
// 440.341 us; speedup vs baseline: 1.2362x; 1.2362x over previous
//
#include <hip/hip_runtime.h>
#include <math.h>

#define B 32
#define C 1536
#define D2 3072
#define L 1024
#define KC 64      // k-chunk per staging pass (16 float4 quads)
#define CH 16      // flash L-chunks -> grid 16x32, 64 wave-partials per b
#define LPW 16     // l's per wave = L/(CH*4)

__device__ inline float dot4(float4 a, float4 b) {
    return a.x * b.x + a.y * b.y + a.z * b.z + a.w * b.w;
}
__device__ inline float4 ld4(const float* p) { return *(const float4*)p; }
__device__ inline void   st4(float* p, float4 v) { *(float4*)p = v; }

// swizzled LDS quad address (float index): row*KC + (q ^ ((row>>2)&7))*4
__device__ inline int sw(int row, int q) {
    return row * KC + ((q ^ ((row >> 2) & 7)) << 2);
}

// ---------------- 32x32 tiled transpose (for phi_w) ----------------
__global__ __launch_bounds__(256) void transpose_k(const float* __restrict__ src,
                                                   float* __restrict__ dst, int n) {
    __shared__ float tile[32][33];
    int bx = blockIdx.x * 32, by = blockIdx.y * 32;
    int tx = threadIdx.x & 31, ty0 = threadIdx.x >> 5;
    #pragma unroll
    for (int r = 0; r < 4; ++r) {
        int ty = ty0 + r * 8;
        tile[ty][tx] = src[(size_t)(by + ty) * n + bx + tx];
    }
    __syncthreads();
    #pragma unroll
    for (int r = 0; r < 4; ++r) {
        int ty = ty0 + r * 8;
        dst[(size_t)(bx + ty) * n + by + tx] = tile[tx][ty];
    }
}

// ---------------- split-K GEMM: 32b x 64j tile, 2x4/thread, 12 kb slices ----------------
// part[(kb*32+b)*N + j] = sum over this block's K-slice of A[b,k]*W[j,k]
__global__ __launch_bounds__(256) void gemm32(const float* __restrict__ A,   // 32 x K
                                              const float* __restrict__ W,   // N x K
                                              float* __restrict__ part,
                                              int N, int K, int kchunks) {
    __shared__ float xs[32 * KC];    // 8 KB
    __shared__ float wsm[64 * KC];   // 16 KB
    int tid = threadIdx.x;
    int j0 = blockIdx.x * 64;
    int kb = blockIdx.y;
    int tb = tid & 15;       // 16 b-groups of 2 rows
    int tj = tid >> 4;       // 16 j-groups of 4 cols

    float4 acc0 = make_float4(0.f, 0.f, 0.f, 0.f);
    float4 acc1 = make_float4(0.f, 0.f, 0.f, 0.f);

    for (int c = 0; c < kchunks; ++c) {
        int k0 = (kb * kchunks + c) * KC;
        __syncthreads();
        #pragma unroll
        for (int p = 0; p < 2; ++p) {
            int f = tid + 256 * p;
            int row = f >> 4, q = f & 15;
            st4(xs + sw(row, q), ld4(A + (size_t)row * K + k0 + 4 * q));
        }
        #pragma unroll
        for (int p = 0; p < 4; ++p) {
            int f = tid + 256 * p;
            int row = f >> 4, q = f & 15;
            st4(wsm + sw(row, q), ld4(W + (size_t)(j0 + row) * K + k0 + 4 * q));
        }
        __syncthreads();
        #pragma unroll
        for (int kq = 0; kq < 16; ++kq) {
            float4 x0 = ld4(xs + sw(2 * tb, kq));
            float4 x1 = ld4(xs + sw(2 * tb + 1, kq));
            float4 w0 = ld4(wsm + sw(4 * tj + 0, kq));
            float4 w1 = ld4(wsm + sw(4 * tj + 1, kq));
            float4 w2 = ld4(wsm + sw(4 * tj + 2, kq));
            float4 w3 = ld4(wsm + sw(4 * tj + 3, kq));
            acc0.x += dot4(x0, w0); acc0.y += dot4(x0, w1);
            acc0.z += dot4(x0, w2); acc0.w += dot4(x0, w3);
            acc1.x += dot4(x1, w0); acc1.y += dot4(x1, w1);
            acc1.z += dot4(x1, w2); acc1.w += dot4(x1, w3);
        }
    }
    st4(part + ((size_t)kb * 32 + 2 * tb + 0) * N + j0 + 4 * tj, acc0);
    st4(part + ((size_t)kb * 32 + 2 * tb + 1) * N + j0 + 4 * tj, acc1);
}

// ---------------- split-K reduce + epilogues ----------------
// mode 0: out = sum + bias (bias may be null)
// mode 2: feats[b*D2+j] = x[b*C+j]; feats[b*D2+C+j] = sum + bias + x
__global__ __launch_bounds__(256) void reduce_part(const float* __restrict__ part,
                                                   const float* __restrict__ bias,
                                                   const float* __restrict__ addx,
                                                   float* __restrict__ out,
                                                   float* __restrict__ feats,
                                                   int N, int mode) {
    int i = blockIdx.x * 256 + threadIdx.x;   // over 32*N
    int b = i / N, j = i % N;
    float s = 0.f;
    #pragma unroll
    for (int kk = 0; kk < 12; ++kk) s += part[((size_t)kk * 32 + b) * N + j];
    if (bias) s += bias[j];
    if (mode == 2) {
        float xv = addx[i];
        feats[(size_t)b * D2 + j] = xv;
        feats[(size_t)b * D2 + C + j] = s + xv;
    } else {
        out[i] = s;
    }
}

// ---------------- split-K reduce + bias + layernorm + relu (32 rows) ----------------
__global__ __launch_bounds__(256) void reduce_ln_relu(const float* __restrict__ part,
                                                      const float* __restrict__ bias,
                                                      const float* __restrict__ g,
                                                      const float* __restrict__ bt,
                                                      float* __restrict__ out) {
    int b = blockIdx.x, tid = threadIdx.x;
    __shared__ float r1[4], r2[4];
    float lv[6];
    float s1 = 0.f, s2 = 0.f;
    #pragma unroll
    for (int t = 0; t < 6; ++t) {
        int c = tid + 256 * t;
        float acc = 0.f;
        #pragma unroll
        for (int kk = 0; kk < 12; ++kk) acc += part[((size_t)kk * 32 + b) * C + c];
        acc += bias[c];
        lv[t] = acc; s1 += acc; s2 += acc * acc;
    }
    #pragma unroll
    for (int off = 32; off > 0; off >>= 1) {
        s1 += __shfl_xor(s1, off, 64);
        s2 += __shfl_xor(s2, off, 64);
    }
    int wave = tid >> 6, lane = tid & 63;
    if (lane == 0) { r1[wave] = s1; r2[wave] = s2; }
    __syncthreads();
    s1 = r1[0] + r1[1] + r1[2] + r1[3];
    s2 = r2[0] + r2[1] + r2[2] + r2[3];
    float mu = s1 / (float)C;
    float var = s2 / (float)C - mu * mu;
    float rstd = 1.0f / sqrtf(var + 1e-5f);
    #pragma unroll
    for (int t = 0; t < 6; ++t) {
        int c = tid + 256 * t;
        float y = (lv[t] - mu) * rstd * g[c] + bt[c];
        out[(size_t)b * C + c] = fmaxf(y, 0.f);
    }
}

// ---------------- flash: scores + online softmax + weighted lfb accumulation ----------------
__global__ __launch_bounds__(256) void flash_k(const float* __restrict__ u,    // 32 x C
                                               const float* __restrict__ lfb,  // 32 x L x C
                                               float* __restrict__ pm,
                                               float* __restrict__ ps,
                                               float* __restrict__ pv) {
    int chunk = blockIdx.x;          // 0..CH-1
    int b = blockIdx.y;              // 0..31
    int wave = threadIdx.x >> 6;     // 0..3
    int lane = threadIdx.x & 63;
    int widx = chunk * 4 + wave;     // 0..63

    const float scale = 39.19183588453085f;  // sqrt(1536)

    float uu[24];
    const float* ub = u + (size_t)b * C;
    #pragma unroll
    for (int t = 0; t < 6; ++t)
        *(float4*)(uu + 4 * t) = ld4(ub + 4 * lane + 256 * t);

    float m = -INFINITY, s = 0.f;
    float vv[24];
    #pragma unroll
    for (int t = 0; t < 24; ++t) vv[t] = 0.f;

    int l0 = chunk * (L / CH) + wave;        // stride 4 within chunk
    for (int i = 0; i < LPW; ++i) {
        int l = l0 + i * 4;
        const float* row = lfb + ((size_t)b * L + l) * C;
        float xx[24];
        #pragma unroll
        for (int t = 0; t < 6; ++t)
            *(float4*)(xx + 4 * t) = ld4(row + 4 * lane + 256 * t);
        float d = 0.f;
        #pragma unroll
        for (int t = 0; t < 24; ++t) d += xx[t] * uu[t];
        #pragma unroll
        for (int off = 32; off > 0; off >>= 1) d += __shfl_xor(d, off, 64);
        float score = d * scale;
        float mn = fmaxf(m, score);
        float alpha = __expf(m - mn);        // 0 when m == -inf
        float p = __expf(score - mn);
        s = s * alpha + p;
        #pragma unroll
        for (int t = 0; t < 24; ++t) vv[t] = vv[t] * alpha + p * xx[t];
        m = mn;
    }

    if (lane == 0) { pm[b * 64 + widx] = m; ps[b * 64 + widx] = s; }
    float* pvb = pv + ((size_t)b * 64 + widx) * C;
    #pragma unroll
    for (int t = 0; t < 6; ++t)
        st4(pvb + 4 * lane + 256 * t, *(float4*)(vv + 4 * t));
}

// ---------------- combine wave-partials -> v[b][c] ----------------
__global__ __launch_bounds__(256) void combine_k(const float* __restrict__ pm,
                                                 const float* __restrict__ ps,
                                                 const float* __restrict__ pv,
                                                 float* __restrict__ v) {
    int cc = blockIdx.x;             // 0..5
    int b = blockIdx.y;              // 0..31
    int tid = threadIdx.x;
    __shared__ float coef[64];
    if (tid < 64) {
        float mj = pm[b * 64 + tid];
        float M = mj;
        #pragma unroll
        for (int off = 32; off > 0; off >>= 1) M = fmaxf(M, __shfl_xor(M, off, 64));
        float ej = expf(mj - M);
        float S = ps[b * 64 + tid] * ej;
        #pragma unroll
        for (int off = 32; off > 0; off >>= 1) S += __shfl_xor(S, off, 64);
        coef[tid] = ej / S;
    }
    __syncthreads();
    int c = cc * 256 + tid;
    float acc = 0.f;
    #pragma unroll 8
    for (int j = 0; j < 64; ++j)
        acc += coef[j] * pv[((size_t)b * 64 + j) * C + c];
    v[(size_t)b * C + c] = acc;
}

// ---------------- final: reduce fcn partials + bias + relu + 4 head dots ----------------
__global__ __launch_bounds__(256) void final_k(const float* __restrict__ partH, // 12 x 32 x D2
                                               const float* __restrict__ fcn_b,
                                               const float* __restrict__ w1, const float* __restrict__ b1,
                                               const float* __restrict__ w2, const float* __restrict__ b2,
                                               const float* __restrict__ w3, const float* __restrict__ b3,
                                               const float* __restrict__ wt, const float* __restrict__ bt,
                                               float* __restrict__ out) {
    int b = blockIdx.x;
    int tid = threadIdx.x;
    float ph0 = 0.f, ph1 = 0.f, ph2 = 0.f, ptv = 0.f;
    #pragma unroll
    for (int t = 0; t < 12; ++t) {
        int j = tid + 256 * t;
        float s = 0.f;
        #pragma unroll
        for (int ss = 0; ss < 12; ++ss)
            s += partH[((size_t)ss * 32 + b) * D2 + j];
        s += fcn_b[j];
        s = fmaxf(s, 0.f);
        ptv += s * wt[j];
        int jj = tid + 256 * (t & 3);
        if (t < 4)       ph0 += s * w1[jj];
        else if (t < 8)  ph1 += s * w2[jj];
        else             ph2 += s * w3[jj];
    }
    #pragma unroll
    for (int off = 32; off > 0; off >>= 1) {
        ph0 += __shfl_xor(ph0, off, 64);
        ph1 += __shfl_xor(ph1, off, 64);
        ph2 += __shfl_xor(ph2, off, 64);
        ptv += __shfl_xor(ptv, off, 64);
    }
    __shared__ float red[4][4];
    int wave = tid >> 6, lane = tid & 63;
    if (lane == 0) {
        red[wave][0] = ph0; red[wave][1] = ph1; red[wave][2] = ph2; red[wave][3] = ptv;
    }
    __syncthreads();
    if (tid < 4) {
        float v = red[0][tid] + red[1][tid] + red[2][tid] + red[3][tid];
        float bias = (tid == 0) ? b1[0] : (tid == 1) ? b2[0] : (tid == 2) ? b3[0] : bt[0];
        out[b * 4 + tid] = v + bias;
    }
}

extern "C" void kernel_launch(void* const* d_in, const int* in_sizes, int n_in,
                              void* d_out, int out_size, void* d_ws, size_t ws_size,
                              hipStream_t stream) {
    (void)in_sizes; (void)n_in; (void)out_size; (void)ws_size;
    const float* x       = (const float*)d_in[0];
    const float* lfb     = (const float*)d_in[1];
    const float* theta_w = (const float*)d_in[2];
    const float* theta_b = (const float*)d_in[3];
    const float* phi_w   = (const float*)d_in[4];
    // d_in[5] = phi_b: additive per-row constant in softmax -> drops out
    const float* gi_w    = (const float*)d_in[6];
    const float* gi_b    = (const float*)d_in[7];
    const float* ln_g    = (const float*)d_in[8];
    const float* ln_b    = (const float*)d_in[9];
    const float* fc_w    = (const float*)d_in[10];
    const float* fc_b    = (const float*)d_in[11];
    const float* fcn_w   = (const float*)d_in[12];
    const float* fcn_b   = (const float*)d_in[13];
    const float* w1 = (const float*)d_in[14]; const float* b1 = (const float*)d_in[15];
    const float* w2 = (const float*)d_in[16]; const float* b2 = (const float*)d_in[17];
    const float* w3 = (const float*)d_in[18]; const float* b3 = (const float*)d_in[19];
    const float* wt = (const float*)d_in[20]; const float* bt = (const float*)d_in[21];
    float* out = (float*)d_out;
    float* w = (float*)d_ws;

    // workspace layout (floats), all disjoint (~37 MB of 768 MiB)
    float* phiT  = w;                  // 2359296
    float* partT = w + 2359296;        // 589824
    float* partU = w + 2949120;        // 589824
    float* partG = w + 3538944;        // 589824
    float* partF = w + 4128768;        // 589824
    float* partH = w + 4718592;        // 1179648
    float* pv    = w + 5898240;        // 3145728
    float* pm    = w + 9043968;        // 2048
    float* ps    = w + 9046016;        // 2048
    float* theta = w + 9048064;        // 49152
    float* u     = w + 9097216;        // 49152
    float* vbuf  = w + 9146368;        // 49152
    float* oln   = w + 9195520;        // 49152
    float* feats = w + 9244672;        // 98304

    transpose_k<<<dim3(48, 48), 256, 0, stream>>>(phi_w, phiT, C);

    // theta = x @ theta_w.T + theta_b
    gemm32<<<dim3(24, 12), 256, 0, stream>>>(x, theta_w, partT, C, C, 2);
    reduce_part<<<192, 256, 0, stream>>>(partT, theta_b, nullptr, theta, nullptr, C, 0);

    // u = theta @ phi_w
    gemm32<<<dim3(24, 12), 256, 0, stream>>>(theta, phiT, partU, C, C, 2);
    reduce_part<<<192, 256, 0, stream>>>(partU, nullptr, nullptr, u, nullptr, C, 0);

    // flash over lfb
    flash_k<<<dim3(CH, B), 256, 0, stream>>>(u, lfb, pm, ps, pv);
    combine_k<<<dim3(6, B), 256, 0, stream>>>(pm, ps, pv, vbuf);

    // o = v @ gi_w.T + gi_b ; oln = relu(LN(o))
    gemm32<<<dim3(24, 12), 256, 0, stream>>>(vbuf, gi_w, partG, C, C, 2);
    reduce_ln_relu<<<B, 256, 0, stream>>>(partG, gi_b, ln_g, ln_b, oln);

    // o2 = oln @ fc_w.T + fc_b ; feats = [x | o2 + x]
    gemm32<<<dim3(24, 12), 256, 0, stream>>>(oln, fc_w, partF, C, C, 2);
    reduce_part<<<192, 256, 0, stream>>>(partF, fc_b, x, nullptr, feats, C, 2);

    // partH = split-K slices of feats @ fcn_w.T
    gemm32<<<dim3(48, 12), 256, 0, stream>>>(feats, fcn_w, partH, D2, D2, 4);

    // reduce + bias + relu + 4 head dots
    final_k<<<B, 256, 0, stream>>>(partH, fcn_b, w1, b1, w2, b2, w3, b3, wt, bt, out);
}